// Round 2
// baseline (145.549 us; speedup 1.0000x reference)
//
#include <hip/hip_runtime.h>

#define BATCH 32768
#define DIM   256
#define NEXP  8
#define MT    64          // rows per tile
#define STRIDE 264        // DIM + 8 bf16 pad (measured 0 bank conflicts)
#define GRID  256         // persistent blocks: ~2 tiles each, pipelined

typedef __bf16 bf16x8 __attribute__((ext_vector_type(8)));
typedef __bf16 bf16x4 __attribute__((ext_vector_type(4)));
typedef float  f32x16 __attribute__((ext_vector_type(16)));

static __device__ __forceinline__ float sigmoid_f(float x) {
    return __builtin_amdgcn_rcpf(1.f + __expf(-x));
}
static __device__ __forceinline__ float tanh_f(float x) {
    return 1.f - 2.f * __builtin_amdgcn_rcpf(__expf(2.f * x) + 1.f);
}

// ---- fused prep (unchanged).
// Blocks 0..255: pack W1/W2 fp32->bf16 into MFMA-B-fragment order.
// Layout (bf16x8 units): dst = [e][nt][ks][kh*32+nl], value j = W[e][nt*32+nl][ks*16+kh*8+j]
// Blocks 256..383: scatter sample indices into per-expert regions.
__global__ void prep_kernel(const float* __restrict__ W1, const float* __restrict__ W2,
                            const float* __restrict__ t,
                            bf16x8* __restrict__ W1p, bf16x8* __restrict__ W2p,
                            int* __restrict__ cursor, int* __restrict__ idxb) {
    const int b = blockIdx.x;
    if (b < 256) {
        const int tid = b * 256 + threadIdx.x;   // = e*8192 + col*32 + ks*2 + kh
        const int kh  = tid & 1;
        const int ks  = (tid >> 1) & 15;
        const int col = (tid >> 5) & 255;
        const int e   = tid >> 13;
        const long src = (long)tid * 8;          // consecutive floats -> coalesced
        const float4 a0 = *(const float4*)(W1 + src);
        const float4 a1 = *(const float4*)(W1 + src + 4);
        const float4 c0 = *(const float4*)(W2 + src);
        const float4 c1 = *(const float4*)(W2 + src + 4);
        bf16x8 w1, w2;
        w1[0] = (__bf16)a0.x; w1[1] = (__bf16)a0.y; w1[2] = (__bf16)a0.z; w1[3] = (__bf16)a0.w;
        w1[4] = (__bf16)a1.x; w1[5] = (__bf16)a1.y; w1[6] = (__bf16)a1.z; w1[7] = (__bf16)a1.w;
        w2[0] = (__bf16)c0.x; w2[1] = (__bf16)c0.y; w2[2] = (__bf16)c0.z; w2[3] = (__bf16)c0.w;
        w2[4] = (__bf16)c1.x; w2[5] = (__bf16)c1.y; w2[6] = (__bf16)c1.z; w2[7] = (__bf16)c1.w;
        const int dst = (e << 13) | ((col >> 5) << 10) | (ks << 6) | (kh << 5) | (col & 31);
        W1p[dst] = w1;
        W2p[dst] = w2;
    } else {
        __shared__ int h[NEXP], base[NEXP];
        if (threadIdx.x < NEXP) h[threadIdx.x] = 0;
        __syncthreads();
        const int i = (b - 256) * 256 + threadIdx.x;
        const int e = min((int)(t[i] * 8.0f), NEXP - 1);
        const int lr = atomicAdd(&h[e], 1);
        __syncthreads();
        if (threadIdx.x < NEXP)
            base[threadIdx.x] = atomicAdd(&cursor[threadIdx.x], h[threadIdx.x]);
        __syncthreads();
        idxb[e * BATCH + base[e] + lr] = i;
    }
}

// ---- grouped fused 2-layer MLP, PIPELINED.
// 256 persistent blocks x 512 threads (8 waves x 32 cols, acc[2] rows).
// Each block grid-strides over ~2 tiles. T14 async-STAGE split: next tile's
// y rows are loaded into registers at the TOP of the iteration (in flight
// under GEMM1+tanh+GEMM2 ~1500cy > 900cy HBM latency), converted + written
// to the single LDS buffer after the post-GEMM2 barrier. Keeps HBM reads
// continuously in flight instead of only during a serial gather phase.
__global__ void __launch_bounds__(512, 2)
mlp_kernel(const float* __restrict__ y,
           const float* __restrict__ scales,
           const float* __restrict__ shifta,
           const float* __restrict__ shiftb,
           const float* __restrict__ b1,
           const float* __restrict__ b2,
           const bf16x8* __restrict__ W1p,
           const bf16x8* __restrict__ W2p,
           const int* __restrict__ cnt,
           const int* __restrict__ idxb,
           float* __restrict__ out) {
    __shared__ __bf16 ab[MT * STRIDE];   // y tile (bf16), then tanh(h); 33.8 KB
    __shared__ int rows[MT];

    const int tx   = threadIdx.x;
    const int wave = tx >> 6;     // 0..7
    const int lane = tx & 63;
    const int nl   = lane & 31;
    const int kh   = lane >> 5;
    const int ncol = wave * 32;   // this wave's 32-col slice

    int c[NEXP], tp[NEXP + 1];
    tp[0] = 0;
#pragma unroll
    for (int e = 0; e < NEXP; ++e) {
        c[e] = cnt[e];
        tp[e + 1] = tp[e] + ((c[e] + MT - 1) >> 6);
    }
    const int total = tp[NEXP];

    const float sa = sigmoid_f(shifta[0]);
    const float sb = sigmoid_f(shiftb[0]);
    const float av = -sa;
    const float bvv = sb;
    const float k1 = 0.5f * (bvv - av);
    const float k2 = 0.5f * (av + bvv);
    const bool needy = (k2 != 0.0f);    // with given inputs k2==0 exactly

    int tile = blockIdx.x;
    if (tile >= total) return;

    int e = 0, rbase, nrows;
    {
#pragma unroll
        for (int j = 0; j < NEXP; ++j) if (tile >= tp[j + 1]) e = j + 1;
        rbase = (tile - tp[e]) * MT;
        nrows = min(MT, c[e] - rbase);
    }

    // ---- prologue: stage first tile directly
    {
        const int* idx_e = idxb + e * BATCH;
#pragma unroll
        for (int pass = 0; pass < 8; ++pass) {
            const int r  = pass * 8 + wave;
            const int rr = min(r, nrows - 1);
            const int g  = idx_e[rbase + rr];
            if (lane == 0) rows[r] = (r < nrows) ? g : -1;
            const float4 v = *(const float4*)(y + (long)g * DIM + lane * 4);
            bf16x4 w;
            w[0] = (__bf16)v.x; w[1] = (__bf16)v.y; w[2] = (__bf16)v.z; w[3] = (__bf16)v.w;
            *(bf16x4*)(ab + r * STRIDE + lane * 4) = w;
        }
    }
    __syncthreads();

    for (;;) {
        // ---- issue next tile's gather into registers (async under compute)
        const int ntile = tile + GRID;
        const bool have_next = (ntile < total);
        int e2 = 0, rbase2 = 0, nrows2 = 0;
        int g2[8];
        float4 v2[8];
        if (have_next) {
#pragma unroll
            for (int j = 0; j < NEXP; ++j) if (ntile >= tp[j + 1]) e2 = j + 1;
            rbase2 = (ntile - tp[e2]) * MT;
            nrows2 = min(MT, c[e2] - rbase2);
            const int* idx2 = idxb + e2 * BATCH;
#pragma unroll
            for (int pass = 0; pass < 8; ++pass) {
                const int r  = pass * 8 + wave;
                const int rr = min(r, nrows2 - 1);
                g2[pass] = idx2[rbase2 + rr];
            }
#pragma unroll
            for (int pass = 0; pass < 8; ++pass)
                v2[pass] = *(const float4*)(y + (long)g2[pass] * DIM + lane * 4);
        }

        const __bf16* apt0 = ab + nl * STRIDE + kh * 8;          // mi=0: rows 0..31
        const __bf16* apt1 = ab + (32 + nl) * STRIDE + kh * 8;   // mi=1: rows 32..63

        // ---- GEMM1: h = y @ W1[e]^T  (A from LDS, B packed-coalesced from L2)
        const bf16x8* w1p = W1p + (e << 13) + (wave << 10) + lane;
        f32x16 acc[2] = {};
#pragma unroll
        for (int ks = 0; ks < 16; ++ks) {
            bf16x8 a0 = *(const bf16x8*)(apt0 + ks * 16);
            bf16x8 a1 = *(const bf16x8*)(apt1 + ks * 16);
            bf16x8 bb = w1p[ks << 6];
            acc[0] = __builtin_amdgcn_mfma_f32_32x32x16_bf16(a0, bb, acc[0], 0, 0, 0);
            acc[1] = __builtin_amdgcn_mfma_f32_32x32x16_bf16(a1, bb, acc[1], 0, 0, 0);
        }
        __syncthreads();   // all GEMM1 reads of ab complete

        // ---- tanh(h + b1) -> ab (C/D: col=nl, row=mi*32+(r&3)+8*(r>>2)+4*kh)
        {
            const int n = ncol + nl;
            const float b1v = b1[(e << 8) | n];
#pragma unroll
            for (int mi = 0; mi < 2; ++mi) {
#pragma unroll
                for (int r = 0; r < 16; ++r) {
                    const int row = mi * 32 + (r & 3) + ((r >> 2) << 3) + (kh << 2);
                    ab[row * STRIDE + n] = (__bf16)tanh_f(acc[mi][r] + b1v);
                }
            }
        }
        __syncthreads();

        // ---- GEMM2: f = h @ W2[e]^T
        const bf16x8* w2p = W2p + (e << 13) + (wave << 10) + lane;
        f32x16 acc2[2] = {};
#pragma unroll
        for (int ks = 0; ks < 16; ++ks) {
            bf16x8 a0 = *(const bf16x8*)(apt0 + ks * 16);
            bf16x8 a1 = *(const bf16x8*)(apt1 + ks * 16);
            bf16x8 bb = w2p[ks << 6];
            acc2[0] = __builtin_amdgcn_mfma_f32_32x32x16_bf16(a0, bb, acc2[0], 0, 0, 0);
            acc2[1] = __builtin_amdgcn_mfma_f32_32x32x16_bf16(a1, bb, acc2[1], 0, 0, 0);
        }

        // ---- epilogue: out = k1*sig(scales)*(f+b2) + k2*y  (reads rows[] before barrier)
        {
            const int n = ncol + nl;
            const float c1  = k1 * sigmoid_f(scales[n]);
            const float b2v = b2[(e << 8) | n];
#pragma unroll
            for (int mi = 0; mi < 2; ++mi) {
#pragma unroll
                for (int r = 0; r < 16; ++r) {
                    const int row = mi * 32 + (r & 3) + ((r >> 2) << 3) + (kh << 2);
                    const int g = rows[row];
                    if (g >= 0) {
                        float res = c1 * (acc2[mi][r] + b2v);
                        if (needy) res += k2 * y[(long)g * DIM + n];
                        out[(long)g * DIM + n] = res;
                    }
                }
            }
        }

        if (!have_next) return;   // uniform across block

        __syncthreads();   // all GEMM2 ds-reads of ab + epilogue rows[] reads done

        // ---- late stage-write: next tile regs -> LDS (vmcnt drained here)
#pragma unroll
        for (int pass = 0; pass < 8; ++pass) {
            const int r = pass * 8 + wave;
            if (lane == 0) rows[r] = (r < nrows2) ? g2[pass] : -1;
            const float4 v = v2[pass];
            bf16x4 w;
            w[0] = (__bf16)v.x; w[1] = (__bf16)v.y; w[2] = (__bf16)v.z; w[3] = (__bf16)v.w;
            *(bf16x4*)(ab + r * STRIDE + lane * 4) = w;
        }
        __syncthreads();

        tile = ntile; e = e2; rbase = rbase2; nrows = nrows2;
    }
}

extern "C" void kernel_launch(void* const* d_in, const int* in_sizes, int n_in,
                              void* d_out, int out_size, void* d_ws, size_t ws_size,
                              hipStream_t stream) {
    const float* t      = (const float*)d_in[0];
    const float* y      = (const float*)d_in[1];
    const float* W1     = (const float*)d_in[2];
    const float* b1     = (const float*)d_in[3];
    const float* W2     = (const float*)d_in[4];
    const float* b2     = (const float*)d_in[5];
    const float* scales = (const float*)d_in[6];
    const float* shifta = (const float*)d_in[7];
    const float* shiftb = (const float*)d_in[8];
    float* out = (float*)d_out;

    char* ws = (char*)d_ws;
    int* cursor = (int*)ws;                               // [8]
    int* idxb   = (int*)(ws + 256);                       // [8][32768]
    bf16x8* W1p = (bf16x8*)(ws + 256 + NEXP * BATCH * 4); // packed 1MB
    bf16x8* W2p = W1p + 65536;

    hipMemsetAsync(cursor, 0, 32, stream);
    prep_kernel<<<384, 256, 0, stream>>>(W1, W2, t, W1p, W2p, cursor, idxb);
    // 256 persistent blocks, ~2 tiles each (max tiles = 8 + 32768/64 = 520)
    mlp_kernel<<<GRID, 512, 0, stream>>>(y, scales, shifta, shiftb, b1, b2,
                                         W1p, W2p, cursor, idxb, out);
}

// Round 3
// 133.276 us; speedup vs baseline: 1.0921x; 1.0921x over previous
//
#include <hip/hip_runtime.h>

#define BATCH 32768
#define DIM   256
#define NEXP  8
#define MT    32          // rows per tile (halved: 2x blocks, 4 blocks/CU resident)
#define STRIDE 264        // DIM + 8 bf16 pad (measured 0 bank conflicts)

typedef __bf16 bf16x8 __attribute__((ext_vector_type(8)));
typedef __bf16 bf16x4 __attribute__((ext_vector_type(4)));
typedef float  f32x16 __attribute__((ext_vector_type(16)));

static __device__ __forceinline__ float sigmoid_f(float x) {
    return __builtin_amdgcn_rcpf(1.f + __expf(-x));
}
static __device__ __forceinline__ float tanh_f(float x) {
    return 1.f - 2.f * __builtin_amdgcn_rcpf(__expf(2.f * x) + 1.f);
}

// ---- fused prep (unchanged).
// Blocks 0..255: pack W1/W2 fp32->bf16 into MFMA-B-fragment order.
// Layout (bf16x8 units): dst = [e][nt][ks][kh*32+nl], value j = W[e][nt*32+nl][ks*16+kh*8+j]
// Blocks 256..383: scatter sample indices into per-expert regions.
__global__ void prep_kernel(const float* __restrict__ W1, const float* __restrict__ W2,
                            const float* __restrict__ t,
                            bf16x8* __restrict__ W1p, bf16x8* __restrict__ W2p,
                            int* __restrict__ cursor, int* __restrict__ idxb) {
    const int b = blockIdx.x;
    if (b < 256) {
        const int tid = b * 256 + threadIdx.x;   // = e*8192 + col*32 + ks*2 + kh
        const int kh  = tid & 1;
        const int ks  = (tid >> 1) & 15;
        const int col = (tid >> 5) & 255;
        const int e   = tid >> 13;
        const long src = (long)tid * 8;          // consecutive floats -> coalesced
        const float4 a0 = *(const float4*)(W1 + src);
        const float4 a1 = *(const float4*)(W1 + src + 4);
        const float4 c0 = *(const float4*)(W2 + src);
        const float4 c1 = *(const float4*)(W2 + src + 4);
        bf16x8 w1, w2;
        w1[0] = (__bf16)a0.x; w1[1] = (__bf16)a0.y; w1[2] = (__bf16)a0.z; w1[3] = (__bf16)a0.w;
        w1[4] = (__bf16)a1.x; w1[5] = (__bf16)a1.y; w1[6] = (__bf16)a1.z; w1[7] = (__bf16)a1.w;
        w2[0] = (__bf16)c0.x; w2[1] = (__bf16)c0.y; w2[2] = (__bf16)c0.z; w2[3] = (__bf16)c0.w;
        w2[4] = (__bf16)c1.x; w2[5] = (__bf16)c1.y; w2[6] = (__bf16)c1.z; w2[7] = (__bf16)c1.w;
        const int dst = (e << 13) | ((col >> 5) << 10) | (ks << 6) | (kh << 5) | (col & 31);
        W1p[dst] = w1;
        W2p[dst] = w2;
    } else {
        __shared__ int h[NEXP], base[NEXP];
        if (threadIdx.x < NEXP) h[threadIdx.x] = 0;
        __syncthreads();
        const int i = (b - 256) * 256 + threadIdx.x;
        const int e = min((int)(t[i] * 8.0f), NEXP - 1);
        const int lr = atomicAdd(&h[e], 1);
        __syncthreads();
        if (threadIdx.x < NEXP)
            base[threadIdx.x] = atomicAdd(&cursor[threadIdx.x], h[threadIdx.x]);
        __syncthreads();
        idxb[e * BATCH + base[e] + lr] = i;
    }
}

// ---- grouped fused 2-layer MLP. 512-thread blocks, 8 waves: each wave
// 32 rows x 32 cols (acc[1], 16 AGPR). MT=32 -> 1032 blocks, LDS 17KB,
// target 4 blocks/CU (32 waves/CU) so independent blocks overlap each
// other's gather / barrier-drain / compute phases (inter-block pipelining;
// intra-block prefetch across __syncthreads is defeated by the compiler's
// vmcnt(0) barrier drain — measured R2 regression).
__global__ void __launch_bounds__(512, 8)
mlp_kernel(const float* __restrict__ y,
           const float* __restrict__ scales,
           const float* __restrict__ shifta,
           const float* __restrict__ shiftb,
           const float* __restrict__ b1,
           const float* __restrict__ b2,
           const bf16x8* __restrict__ W1p,
           const bf16x8* __restrict__ W2p,
           const int* __restrict__ cnt,
           const int* __restrict__ idxb,
           float* __restrict__ out) {
    __shared__ __bf16 ab[MT * STRIDE];   // y tile (bf16), then tanh(h); 16.9 KB
    __shared__ int rows[MT];

    const int tx   = threadIdx.x;
    const int wave = tx >> 6;     // 0..7
    const int lane = tx & 63;
    const int nl   = lane & 31;
    const int kh   = lane >> 5;
    const int ncol = wave * 32;   // this wave's 32-col slice

    int c[NEXP], tp[NEXP + 1];
    tp[0] = 0;
#pragma unroll
    for (int e = 0; e < NEXP; ++e) {
        c[e] = cnt[e];
        tp[e + 1] = tp[e] + ((c[e] + MT - 1) >> 5);
    }
    const int total = tp[NEXP];

    const float sa = sigmoid_f(shifta[0]);
    const float sb = sigmoid_f(shiftb[0]);
    const float av = -sa;
    const float bvv = sb;
    const float k1 = 0.5f * (bvv - av);
    const float k2 = 0.5f * (av + bvv);
    const bool needy = (k2 != 0.0f);    // with given inputs k2==0 exactly

    for (int tile = blockIdx.x; tile < total; tile += gridDim.x) {
        int e = 0;
#pragma unroll
        for (int j = 0; j < NEXP; ++j) if (tile >= tp[j + 1]) e = j + 1;
        const int rbase = (tile - tp[e]) * MT;
        const int nrows = min(MT, c[e] - rbase);
        const int* idx_e = idxb + e * BATCH;

        __syncthreads();   // previous iteration's readers of ab/rows done
        // stage gathered y rows -> bf16 LDS tile; one row per wave per pass
#pragma unroll
        for (int pass = 0; pass < 4; ++pass) {
            const int r  = pass * 8 + wave;
            const int rr = min(r, nrows - 1);
            const int g  = idx_e[rbase + rr];
            if (lane == 0) rows[r] = (r < nrows) ? g : -1;
            const float4 v = *(const float4*)(y + (long)g * DIM + lane * 4);
            bf16x4 w;
            w[0] = (__bf16)v.x; w[1] = (__bf16)v.y; w[2] = (__bf16)v.z; w[3] = (__bf16)v.w;
            *(bf16x4*)(ab + r * STRIDE + lane * 4) = w;
        }
        __syncthreads();

        const __bf16* apt0 = ab + nl * STRIDE + kh * 8;   // rows 0..31

        // ---- GEMM1: h = y @ W1[e]^T  (A from LDS, B packed-coalesced from L2)
        const bf16x8* w1p = W1p + (e << 13) + (wave << 10) + lane;
        f32x16 acc = {};
#pragma unroll
        for (int ks = 0; ks < 16; ++ks) {
            bf16x8 a0 = *(const bf16x8*)(apt0 + ks * 16);
            bf16x8 bb = w1p[ks << 6];
            acc = __builtin_amdgcn_mfma_f32_32x32x16_bf16(a0, bb, acc, 0, 0, 0);
        }
        __syncthreads();   // all GEMM1 reads of ab complete

        // ---- tanh(h + b1) -> ab (C/D: col=nl, row=(r&3)+8*(r>>2)+4*kh)
        {
            const int n = ncol + nl;
            const float b1v = b1[(e << 8) | n];
#pragma unroll
            for (int r = 0; r < 16; ++r) {
                const int row = (r & 3) + ((r >> 2) << 3) + (kh << 2);
                ab[row * STRIDE + n] = (__bf16)tanh_f(acc[r] + b1v);
            }
        }
        __syncthreads();

        // ---- GEMM2: f = h @ W2[e]^T
        const bf16x8* w2p = W2p + (e << 13) + (wave << 10) + lane;
        f32x16 acc2 = {};
#pragma unroll
        for (int ks = 0; ks < 16; ++ks) {
            bf16x8 a0 = *(const bf16x8*)(apt0 + ks * 16);
            bf16x8 bb = w2p[ks << 6];
            acc2 = __builtin_amdgcn_mfma_f32_32x32x16_bf16(a0, bb, acc2, 0, 0, 0);
        }

        // ---- epilogue: out = k1*sig(scales)*(f+b2) + k2*y
        {
            const int n = ncol + nl;
            const float c1  = k1 * sigmoid_f(scales[n]);
            const float b2v = b2[(e << 8) | n];
#pragma unroll
            for (int r = 0; r < 16; ++r) {
                const int row = (r & 3) + ((r >> 2) << 3) + (kh << 2);
                const int g = rows[row];
                if (g >= 0) {
                    float res = c1 * (acc2[r] + b2v);
                    if (needy) res += k2 * y[(long)g * DIM + n];
                    out[(long)g * DIM + n] = res;
                }
            }
        }
    }
}

extern "C" void kernel_launch(void* const* d_in, const int* in_sizes, int n_in,
                              void* d_out, int out_size, void* d_ws, size_t ws_size,
                              hipStream_t stream) {
    const float* t      = (const float*)d_in[0];
    const float* y      = (const float*)d_in[1];
    const float* W1     = (const float*)d_in[2];
    const float* b1     = (const float*)d_in[3];
    const float* W2     = (const float*)d_in[4];
    const float* b2     = (const float*)d_in[5];
    const float* scales = (const float*)d_in[6];
    const float* shifta = (const float*)d_in[7];
    const float* shiftb = (const float*)d_in[8];
    float* out = (float*)d_out;

    char* ws = (char*)d_ws;
    int* cursor = (int*)ws;                               // [8]
    int* idxb   = (int*)(ws + 256);                       // [8][32768]
    bf16x8* W1p = (bf16x8*)(ws + 256 + NEXP * BATCH * 4); // packed 1MB
    bf16x8* W2p = W1p + 65536;

    hipMemsetAsync(cursor, 0, 32, stream);
    prep_kernel<<<384, 256, 0, stream>>>(W1, W2, t, W1p, W2p, cursor, idxb);
    // max tiles = 8 + 32768/32 = 1032
    mlp_kernel<<<1032, 512, 0, stream>>>(y, scales, shifta, shiftb, b1, b2,
                                         W1p, W2p, cursor, idxb, out);
}

// Round 5
// 124.777 us; speedup vs baseline: 1.1665x; 1.0681x over previous
//
#include <hip/hip_runtime.h>

#define BATCH 32768
#define DIM   256
#define NEXP  8
#define MT    32          // rows per tile
#define STRIDE 264        // DIM + 8 bf16 pad (measured 0 bank conflicts)

typedef __bf16 bf16x8 __attribute__((ext_vector_type(8)));
typedef __bf16 bf16x4 __attribute__((ext_vector_type(4)));
typedef float  f32x16 __attribute__((ext_vector_type(16)));

static __device__ __forceinline__ float sigmoid_f(float x) {
    return __builtin_amdgcn_rcpf(1.f + __expf(-x));
}
static __device__ __forceinline__ float tanh_f(float x) {
    return 1.f - 2.f * __builtin_amdgcn_rcpf(__expf(2.f * x) + 1.f);
}

// ---- fused prep (unchanged).
// Blocks 0..255: pack W1/W2 fp32->bf16 into MFMA-B-fragment order.
// Layout (bf16x8 units): dst = [e][nt][ks][kh*32+nl], value j = W[e][nt*32+nl][ks*16+kh*8+j]
// Blocks 256..383: scatter sample indices into per-expert regions.
__global__ void prep_kernel(const float* __restrict__ W1, const float* __restrict__ W2,
                            const float* __restrict__ t,
                            bf16x8* __restrict__ W1p, bf16x8* __restrict__ W2p,
                            int* __restrict__ cursor, int* __restrict__ idxb) {
    const int b = blockIdx.x;
    if (b < 256) {
        const int tid = b * 256 + threadIdx.x;   // = e*8192 + col*32 + ks*2 + kh
        const int kh  = tid & 1;
        const int ks  = (tid >> 1) & 15;
        const int col = (tid >> 5) & 255;
        const int e   = tid >> 13;
        const long src = (long)tid * 8;          // consecutive floats -> coalesced
        const float4 a0 = *(const float4*)(W1 + src);
        const float4 a1 = *(const float4*)(W1 + src + 4);
        const float4 c0 = *(const float4*)(W2 + src);
        const float4 c1 = *(const float4*)(W2 + src + 4);
        bf16x8 w1, w2;
        w1[0] = (__bf16)a0.x; w1[1] = (__bf16)a0.y; w1[2] = (__bf16)a0.z; w1[3] = (__bf16)a0.w;
        w1[4] = (__bf16)a1.x; w1[5] = (__bf16)a1.y; w1[6] = (__bf16)a1.z; w1[7] = (__bf16)a1.w;
        w2[0] = (__bf16)c0.x; w2[1] = (__bf16)c0.y; w2[2] = (__bf16)c0.z; w2[3] = (__bf16)c0.w;
        w2[4] = (__bf16)c1.x; w2[5] = (__bf16)c1.y; w2[6] = (__bf16)c1.z; w2[7] = (__bf16)c1.w;
        const int dst = (e << 13) | ((col >> 5) << 10) | (ks << 6) | (kh << 5) | (col & 31);
        W1p[dst] = w1;
        W2p[dst] = w2;
    } else {
        __shared__ int h[NEXP], base[NEXP];
        if (threadIdx.x < NEXP) h[threadIdx.x] = 0;
        __syncthreads();
        const int i = (b - 256) * 256 + threadIdx.x;
        const int e = min((int)(t[i] * 8.0f), NEXP - 1);
        const int lr = atomicAdd(&h[e], 1);
        __syncthreads();
        if (threadIdx.x < NEXP)
            base[threadIdx.x] = atomicAdd(&cursor[threadIdx.x], h[threadIdx.x]);
        __syncthreads();
        idxb[e * BATCH + base[e] + lr] = i;
    }
}

// ---- grouped fused 2-layer MLP, expert-pinned blocks, weights in registers.
// 256 blocks (1/CU) x 512 threads (8 waves x 32 cols). Block b owns expert
// b>>5 and processes its tiles (b&31), +32, ... (~4-5 tiles). Both GEMMs'
// B-fragments live in 128 VGPRs (loaded once — inner loops are pure
// ds_read_b128+MFMA, no L2 on the critical path; R3 showed per-MFMA L2
// loads with a 32-VGPR budget serialize at ~L2 latency per step). Next
// tile's y rows prefetch into regs under G1+tanh+G2.
__global__ void __launch_bounds__(512, 2)
mlp_kernel(const float* __restrict__ y,
           const float* __restrict__ scales,
           const float* __restrict__ shifta,
           const float* __restrict__ shiftb,
           const float* __restrict__ b1,
           const float* __restrict__ b2,
           const bf16x8* __restrict__ W1p,
           const bf16x8* __restrict__ W2p,
           const int* __restrict__ cnt,
           const int* __restrict__ idxb,
           float* __restrict__ out) {
    __shared__ __bf16 ab[MT * STRIDE];   // y tile (bf16), then tanh(h); 16.9 KB
    __shared__ int rows[MT];

    const int tx   = threadIdx.x;
    const int wave = tx >> 6;     // 0..7
    const int lane = tx & 63;
    const int nl   = lane & 31;
    const int kh   = lane >> 5;
    const int n    = wave * 32 + nl;   // this thread's output column (fixed)

    const int e    = blockIdx.x >> 5;   // expert pinned to block
    const int slot = blockIdx.x & 31;   // which tile-stripe of this expert
    const int ce   = cnt[e];
    const int nt_e = (ce + MT - 1) >> 5;
    if (slot >= nt_e) return;           // uniform per block (never with random data)
    const int* idx_e = idxb + e * BATCH;

    // ---- load both GEMMs' B-fragments into registers (once per block)
    const bf16x8* w1p = W1p + (e << 13) + (wave << 10) + lane;
    const bf16x8* w2p = W2p + (e << 13) + (wave << 10) + lane;
    bf16x8 wA[16], wB[16];
#pragma unroll
    for (int ks = 0; ks < 16; ++ks) {
        wA[ks] = w1p[ks << 6];
        wB[ks] = w2p[ks << 6];
    }

    // ---- hoisted per-thread epilogue constants (e and n fixed)
    const float sa = sigmoid_f(shifta[0]);
    const float sb = sigmoid_f(shiftb[0]);
    const float k1 = 0.5f * (sb + sa);           // 0.5*(b-a), a=-sa, b=sb
    const float k2 = 0.5f * (sb - sa);           // 0.5*(a+b)
    const bool needy = (k2 != 0.0f);             // with given inputs k2==0 exactly
    const float c1  = k1 * sigmoid_f(scales[n]);
    const float b1v = b1[(e << 8) | n];
    const float b2v = b2[(e << 8) | n];

    // ---- prologue: stage first tile
    int ti = slot;
    int nrows = min(MT, ce - ti * MT);
    {
        const int rbase = ti * MT;
#pragma unroll
        for (int p = 0; p < 4; ++p) {
            const int r  = p * 8 + wave;
            const int rr = min(r, nrows - 1);
            const int g  = idx_e[rbase + rr];
            if (lane == 0) rows[r] = (r < nrows) ? g : -1;
            const float4 v = *(const float4*)(y + (long)g * DIM + lane * 4);
            bf16x4 w;
            w[0] = (__bf16)v.x; w[1] = (__bf16)v.y; w[2] = (__bf16)v.z; w[3] = (__bf16)v.w;
            *(bf16x4*)(ab + r * STRIDE + lane * 4) = w;
        }
    }
    __syncthreads();

    for (;;) {
        // ---- issue next tile's gather into regs (covered by G1+tanh+G2)
        const int ti2 = ti + 32;
        const bool have_next = (ti2 < nt_e);
        int nrows2 = 0;
        int g2v[4];
        float4 v2[4];
        if (have_next) {
            nrows2 = min(MT, ce - ti2 * MT);
            const int rbase2 = ti2 * MT;
#pragma unroll
            for (int p = 0; p < 4; ++p) {
                const int r  = p * 8 + wave;
                const int rr = min(r, nrows2 - 1);
                g2v[p] = idx_e[rbase2 + rr];
            }
#pragma unroll
            for (int p = 0; p < 4; ++p)
                v2[p] = *(const float4*)(y + (long)g2v[p] * DIM + lane * 4);
        }

        const __bf16* apt0 = ab + nl * STRIDE + kh * 8;   // A-frag base, rows 0..31

        // ---- GEMM1: h = y @ W1[e]^T   (pure LDS + reg-resident B)
        f32x16 acc = {};
#pragma unroll
        for (int ks = 0; ks < 16; ++ks) {
            bf16x8 a0 = *(const bf16x8*)(apt0 + ks * 16);
            acc = __builtin_amdgcn_mfma_f32_32x32x16_bf16(a0, wA[ks], acc, 0, 0, 0);
        }
        __syncthreads();   // all GEMM1 reads of ab complete

        // ---- tanh(h + b1) -> ab (C/D: col=nl, row=(r&3)+8*(r>>2)+4*kh)
#pragma unroll
        for (int r = 0; r < 16; ++r) {
            const int row = (r & 3) + ((r >> 2) << 3) + (kh << 2);
            ab[row * STRIDE + n] = (__bf16)tanh_f(acc[r] + b1v);
        }
        __syncthreads();

        // ---- GEMM2: f = h @ W2[e]^T
        f32x16 acc2 = {};
#pragma unroll
        for (int ks = 0; ks < 16; ++ks) {
            bf16x8 a0 = *(const bf16x8*)(apt0 + ks * 16);
            acc2 = __builtin_amdgcn_mfma_f32_32x32x16_bf16(a0, wB[ks], acc2, 0, 0, 0);
        }

        // ---- epilogue: out = k1*sig(scales)*(f+b2) + k2*y  (rows[] still current)
#pragma unroll
        for (int r = 0; r < 16; ++r) {
            const int row = (r & 3) + ((r >> 2) << 3) + (kh << 2);
            const int g = rows[row];
            if (g >= 0) {
                float res = c1 * (acc2[r] + b2v);
                if (needy) res += k2 * y[(long)g * DIM + n];
                out[(long)g * DIM + n] = res;
            }
        }

        if (!have_next) return;   // uniform across block

        __syncthreads();   // GEMM2 ds-reads + epilogue rows[] reads done

        // ---- late stage-write: prefetched regs -> LDS
#pragma unroll
        for (int p = 0; p < 4; ++p) {
            const int r = p * 8 + wave;
            if (lane == 0) rows[r] = (r < nrows2) ? g2v[p] : -1;
            const float4 v = v2[p];
            bf16x4 w;
            w[0] = (__bf16)v.x; w[1] = (__bf16)v.y; w[2] = (__bf16)v.z; w[3] = (__bf16)v.w;
            *(bf16x4*)(ab + r * STRIDE + lane * 4) = w;
        }
        __syncthreads();

        ti = ti2; nrows = nrows2;
    }
}

extern "C" void kernel_launch(void* const* d_in, const int* in_sizes, int n_in,
                              void* d_out, int out_size, void* d_ws, size_t ws_size,
                              hipStream_t stream) {
    const float* t      = (const float*)d_in[0];
    const float* y      = (const float*)d_in[1];
    const float* W1     = (const float*)d_in[2];
    const float* b1     = (const float*)d_in[3];
    const float* W2     = (const float*)d_in[4];
    const float* b2     = (const float*)d_in[5];
    const float* scales = (const float*)d_in[6];
    const float* shifta = (const float*)d_in[7];
    const float* shiftb = (const float*)d_in[8];
    float* out = (float*)d_out;

    char* ws = (char*)d_ws;
    int* cursor = (int*)ws;                               // [8]
    int* idxb   = (int*)(ws + 256);                       // [8][32768]
    bf16x8* W1p = (bf16x8*)(ws + 256 + NEXP * BATCH * 4); // packed 1MB
    bf16x8* W2p = W1p + 65536;

    hipMemsetAsync(cursor, 0, 32, stream);
    prep_kernel<<<384, 256, 0, stream>>>(W1, W2, t, W1p, W2p, cursor, idxb);
    // 256 expert-pinned blocks (32 per expert), 1 block/CU
    mlp_kernel<<<256, 512, 0, stream>>>(y, scales, shifta, shiftb, b1, b2,
                                        W1p, W2p, cursor, idxb, out);
}